// Round 1
// baseline (220.249 us; speedup 1.0000x reference)
//
#include <hip/hip_runtime.h>

// Depth-3 Haar wavelet packet transform along last dim (S=8192), rows = B*C = 4096.
// out[row, n*1024 + j] = c^3 * sum_t (-1)^(b1*t0 + b2*t1 + b3*t2) x[row, 8j+t],
// n = 4*b1 + 2*b2 + b3, c^3 = 2^{-1.5}.

#define C3 0.35355339059327373f
#define ROW_LEN 8192u       // floats per (b,c) row
#define ROW_VEC4 2048u      // float4 per row
#define NODE_LEN 1024u      // floats per sub-band

__global__ __launch_bounds__(256) void swpt3_kernel(const float4* __restrict__ x,
                                                    float* __restrict__ out,
                                                    unsigned nvec4) {
    const unsigned g = blockIdx.x * 256u + threadIdx.x;
    if (g >= nvec4) return;

    const float4 v = x[g];

    // level 1 within the float4
    const float s0 = v.x + v.y, d0 = v.x - v.y;
    const float s1 = v.z + v.w, d1 = v.z - v.w;
    // level 2 (unscaled): node-base nb = 4*b1 + 2*b2
    const float e0 = s0 + s1;   // b1=0,b2=0 -> nb=0
    const float e2 = s0 - s1;   // b1=0,b2=1 -> nb=2
    const float e4 = d0 + d1;   // b1=1,b2=0 -> nb=4
    const float e6 = d0 - d1;   // b1=1,b2=1 -> nb=6

    // level 3: adjacent lanes hold adjacent level-2 positions q (parity = g&1,
    // valid since ROW_VEC4 is even). Even lane -> b3=0 node, odd lane -> b3=1.
    const int p = (int)(g & 1u);
    const float f0 = __shfl_xor(e0, 1);
    const float f2 = __shfl_xor(e2, 1);
    const float f4 = __shfl_xor(e4, 1);
    const float f6 = __shfl_xor(e6, 1);

    // even lane: e + f (=v2[2j]+v2[2j+1]); odd lane: f - e (=v2[2j]-v2[2j+1])
    const float a0 = p ? -e0 : e0;
    const float a2 = p ? -e2 : e2;
    const float a4 = p ? -e4 : e4;
    const float a6 = p ? -e6 : e6;
    const float r0 = (f0 + a0) * C3;
    const float r2 = (f2 + a2) * C3;
    const float r4 = (f4 + a4) * C3;
    const float r6 = (f6 + a6) * C3;

    const unsigned row = g >> 11;          // g / ROW_VEC4
    const unsigned q   = g & (ROW_VEC4 - 1u);
    const unsigned j   = q >> 1;
    float* o = out + (size_t)row * ROW_LEN + (unsigned)p * NODE_LEN + j;
    o[0]            = r0;
    o[2u * NODE_LEN] = r2;
    o[4u * NODE_LEN] = r4;
    o[6u * NODE_LEN] = r6;
}

extern "C" void kernel_launch(void* const* d_in, const int* in_sizes, int n_in,
                              void* d_out, int out_size, void* d_ws, size_t ws_size,
                              hipStream_t stream) {
    const float4* x = (const float4*)d_in[0];
    float* out = (float*)d_out;
    const unsigned n = (unsigned)in_sizes[0];      // 64*64*8192 = 33,554,432
    const unsigned nvec4 = n / 4u;                 // 8,388,608
    const unsigned blocks = (nvec4 + 255u) / 256u; // 32,768
    swpt3_kernel<<<blocks, 256, 0, stream>>>(x, out, nvec4);
}

// Round 2
// 218.590 us; speedup vs baseline: 1.0076x; 1.0076x over previous
//
#include <hip/hip_runtime.h>

// Depth-3 Haar wavelet packet transform along last dim (S=8192), rows = B*C = 4096.
// out[row, n*1024 + j] = c^3 * sum_t (-1)^(b1*t0 + b2*t1 + b3*t2) x[row, 8j+t],
// n = 4*b1 + 2*b2 + b3, c^3 = 2^{-1.5}.
//
// Block = 256 threads, one 256-float4 chunk of a row (1024 inputs -> 1024 outputs).
// Stage 1: float4 load, 2-level butterfly in-register, level-3 via shfl_xor(1),
//          4 scalar LDS writes (2-way bank aliasing, free).
// Stage 2: ds_read_b128 (16B/lane contiguous, conflict-free) + one float4 store
//          (consecutive lanes -> 512B contiguous per node).

#define C3 0.35355339059327373f

__global__ __launch_bounds__(256) void swpt3_kernel(const float4* __restrict__ x,
                                                    float* __restrict__ out) {
    __shared__ float lds[1024];   // [node 0..7][j 0..127]

    const unsigned t   = threadIdx.x;
    const unsigned b   = blockIdx.x;
    const unsigned row = b >> 3;          // 8 chunks per row
    const unsigned ch  = b & 7u;

    const float4 v = x[(size_t)row * 2048u + ch * 256u + t];

    // level 1 within the float4
    const float s0 = v.x + v.y, d0 = v.x - v.y;
    const float s1 = v.z + v.w, d1 = v.z - v.w;
    // level 2 (unscaled): node-base nb = 4*b1 + 2*b2
    const float e0 = s0 + s1;   // nb=0
    const float e2 = s0 - s1;   // nb=2
    const float e4 = d0 + d1;   // nb=4
    const float e6 = d0 - d1;   // nb=6

    // level 3: adjacent lanes hold adjacent level-2 positions (parity = t&1).
    const int p = (int)(t & 1u);
    const float f0 = __shfl_xor(e0, 1);
    const float f2 = __shfl_xor(e2, 1);
    const float f4 = __shfl_xor(e4, 1);
    const float f6 = __shfl_xor(e6, 1);

    const float a0 = p ? -e0 : e0;
    const float a2 = p ? -e2 : e2;
    const float a4 = p ? -e4 : e4;
    const float a6 = p ? -e6 : e6;
    const float r0 = (f0 + a0) * C3;   // node p
    const float r2 = (f2 + a2) * C3;   // node 2+p
    const float r4 = (f4 + a4) * C3;   // node 4+p
    const float r6 = (f6 + a6) * C3;   // node 6+p

    const unsigned j = t >> 1;          // 0..127
    lds[(0u + p) * 128u + j] = r0;
    lds[(2u + p) * 128u + j] = r2;
    lds[(4u + p) * 128u + j] = r4;
    lds[(6u + p) * 128u + j] = r6;

    __syncthreads();

    // regroup: thread t stores float4 #t of the block's 1024 outputs
    const float4 r = ((const float4*)lds)[t];           // lds[t*4 .. t*4+3] = node t>>5, j=4*(t&31)
    const unsigned n = t >> 5;
    const unsigned m = t & 31u;
    float4* o = (float4*)(out + (size_t)row * 8192u + n * 1024u + ch * 128u + 4u * m);
    *o = r;
}

extern "C" void kernel_launch(void* const* d_in, const int* in_sizes, int n_in,
                              void* d_out, int out_size, void* d_ws, size_t ws_size,
                              hipStream_t stream) {
    const float4* x = (const float4*)d_in[0];
    float* out = (float*)d_out;
    // 64*64*8192 floats = 8,388,608 float4 = 32768 blocks x 256 threads, exact.
    swpt3_kernel<<<32768, 256, 0, stream>>>(x, out);
}